// Round 11
// baseline (161.223 us; speedup 1.0000x reference)
//
#include <hip/hip_runtime.h>
#include <hip/hip_bf16.h>

// MHA: out = softmax((x@Wq^T)(x@Wk^T)^T / sqrt(D)) (x@Wv^T) @ Wo^T
// B=2, S=2048, E=1024, H=16, D=64.

typedef __attribute__((ext_vector_type(8))) short short8;
typedef __attribute__((ext_vector_type(4))) float f32x4;
typedef __attribute__((ext_vector_type(4))) unsigned short us4;
typedef __attribute__((ext_vector_type(4))) int i32x4;

#define MFMA16(a, b, c) __builtin_amdgcn_mfma_f32_16x16x32_bf16(a, b, c, 0, 0, 0)

static constexpr int B = 2;
static constexpr int S = 2048;
static constexpr int E = 1024;
static constexpr int H = 16;
static constexpr int D = 64;
static constexpr int M = B * S;               // 4096 rows in projection GEMMs
static constexpr size_t NE = (size_t)M * E;   // activation elements
static constexpr size_t NW = (size_t)E * E;   // weight elements

// round-to-nearest-even fp32 -> bf16 (bit pattern as ushort)
static __device__ __forceinline__ unsigned short f2bf(float x) {
  unsigned int u = __float_as_uint(x);
  unsigned int r = (u + 0x7FFFu + ((u >> 16) & 1u)) >> 16;
  return (unsigned short)r;
}

// packed fp32x2 -> bf16x2 (RNE), single HW instruction; lo in low 16 bits
static __device__ __forceinline__ int cvt_pk_bf16(float lo, float hi) {
  int r;
  asm("v_cvt_pk_bf16_f32 %0, %1, %2" : "=v"(r) : "v"(lo), "v"(hi));
  return r;
}

// async global -> LDS, 16B per lane. LDS dest = wave-uniform base + lane*16.
static __device__ __forceinline__ void gload_lds16(const unsigned short* g,
                                                   unsigned short* l) {
  __builtin_amdgcn_global_load_lds(
      (const __attribute__((address_space(1))) unsigned int*)g,
      (__attribute__((address_space(3))) unsigned int*)l, 16, 0, 0);
}

// ---------------- fp32 -> bf16 conversion (single launch, z-indexed) ------
__global__ void cvt_all_kernel(const float* __restrict__ s0,
                               const float* __restrict__ s1,
                               const float* __restrict__ s2,
                               const float* __restrict__ s3,
                               const float* __restrict__ s4,
                               const float* __restrict__ s5,
                               const float* __restrict__ s6,
                               unsigned short* __restrict__ d0,
                               unsigned short* __restrict__ d1,
                               unsigned short* __restrict__ d2,
                               unsigned short* __restrict__ d3,
                               unsigned short* __restrict__ d4,
                               unsigned short* __restrict__ d5,
                               unsigned short* __restrict__ d6, int nAct4,
                               int nW4) {
  const int z = blockIdx.y;
  const float* srcs[7] = {s0, s1, s2, s3, s4, s5, s6};
  unsigned short* dsts[7] = {d0, d1, d2, d3, d4, d5, d6};
  const float* src = srcs[z];
  unsigned short* dst = dsts[z];
  const int n4 = (z < 3) ? nAct4 : nW4;
  for (int i = blockIdx.x * blockDim.x + threadIdx.x; i < n4;
       i += gridDim.x * blockDim.x) {
    float4 v = reinterpret_cast<const float4*>(src)[i];
    ushort4 o;
    o.x = f2bf(v.x); o.y = f2bf(v.y); o.z = f2bf(v.z); o.w = f2bf(v.w);
    reinterpret_cast<ushort4*>(dst)[i] = o;
  }
}

// ---------------- fused QKV projection GEMM (double-buffered) -------------
// grid (M/128, E/128, 3). 128x128 tile, BK=32, 4 waves 2x2, global_load_lds
// staging, 2-phase: STAGE(next) -> compute(cur) -> one barrier per K-step.
// z==0: Q -> Qh[B][H][S][D] * 0.125*log2(e)   z==1: K -> Kh[B][H][S][D]
// z==2: V -> Vt[B][H][D][S]
__global__ __launch_bounds__(256) void gemm_proj_kernel(
    const unsigned short* __restrict__ xq, const unsigned short* __restrict__ xk,
    const unsigned short* __restrict__ xv, const unsigned short* __restrict__ wq,
    const unsigned short* __restrict__ wk, const unsigned short* __restrict__ wv,
    unsigned short* __restrict__ Qh, unsigned short* __restrict__ Kh,
    unsigned short* __restrict__ Vt) {
  __shared__ __align__(16) unsigned short As[2][128 * 32];
  __shared__ __align__(16) unsigned short Bs[2][128 * 32];

  const int which = blockIdx.z;
  const unsigned short* A = (which == 0) ? xq : ((which == 1) ? xk : xv);
  const unsigned short* W = (which == 0) ? wq : ((which == 1) ? wk : wv);

  const int wave = threadIdx.x >> 6;
  const int lane = threadIdx.x & 63;
  const int lr = lane & 15;
  const int lk = (lane >> 4) * 8;
  const int m0 = blockIdx.x * 128;
  const int n0 = blockIdx.y * 128;
  const int wm = (wave >> 1) * 64;
  const int wn = (wave & 1) * 64;
  const int srow = lane >> 2;        // row within 16-row staging chunk
  const int scol = (lane & 3) * 8;   // element col within BK=32

  f32x4 acc[4][4];
  const f32x4 fz = {0.f, 0.f, 0.f, 0.f};
#pragma unroll
  for (int i = 0; i < 4; ++i)
#pragma unroll
    for (int j = 0; j < 4; ++j) acc[i][j] = fz;

#define STAGE_G(bb, kk)                                                       \
  {                                                                           \
    _Pragma("unroll") for (int i = 0; i < 2; ++i) {                           \
      const int c = wave * 2 + i;                                             \
      const int row = c * 16 + srow;                                          \
      gload_lds16(A + (size_t)(m0 + row) * E + (kk) + scol, &As[bb][c * 512]);\
      gload_lds16(W + (size_t)(n0 + row) * E + (kk) + scol, &Bs[bb][c * 512]);\
    }                                                                         \
  }

  STAGE_G(0, 0);
  __syncthreads();
  int buf = 0;
  for (int kk = 0; kk < E; kk += 32) {
    if (kk + 32 < E) STAGE_G(buf ^ 1, kk + 32);  // prefetch next K-tile
    short8 af[4], bw[4];
#pragma unroll
    for (int i = 0; i < 4; ++i)
      af[i] = *reinterpret_cast<const short8*>(
          &As[buf][(wm + i * 16 + lr) * 32 + lk]);
#pragma unroll
    for (int j = 0; j < 4; ++j)
      bw[j] = *reinterpret_cast<const short8*>(
          &Bs[buf][(wn + j * 16 + lr) * 32 + lk]);
#pragma unroll
    for (int i = 0; i < 4; ++i)
#pragma unroll
      for (int j = 0; j < 4; ++j) acc[i][j] = MFMA16(af[i], bw[j], acc[i][j]);
    __syncthreads();  // drains vmcnt(0): next tile staged; reads done
    buf ^= 1;
  }
#undef STAGE_G

  const int rbase = (lane >> 4) * 4;
#pragma unroll
  for (int i = 0; i < 4; ++i) {
#pragma unroll
    for (int j = 0; j < 4; ++j) {
      const int col = n0 + wn + j * 16 + lr;
      const int h = col >> 6, d = col & 63;
#pragma unroll
      for (int r = 0; r < 4; ++r) {
        const int row = m0 + wm + i * 16 + rbase + r;
        const int b = row >> 11, s = row & (S - 1);
        const float v = acc[i][j][r];
        if (which == 0) {
          // 0.125 * log2(e): QK scores land in log2 domain for native v_exp
          Qh[(((size_t)b * H + h) * S + s) * D + d] = f2bf(v * 0.18033688f);
        } else if (which == 1) {
          Kh[(((size_t)b * H + h) * S + s) * D + d] = f2bf(v);
        } else {
          Vt[(((size_t)b * H + h) * D + d) * S + s] = f2bf(v);
        }
      }
    }
  }
}

// ---------------- output GEMM: out = X @ Wo^T (128x64 tile, dbuf) ---------
// grid (M/128, E/64) = 512 blocks -> 2 blocks/CU for overlap.
__global__ __launch_bounds__(256) void gemm_out_kernel(
    const unsigned short* __restrict__ X, const unsigned short* __restrict__ Wo,
    float* __restrict__ out) {
  __shared__ __align__(16) unsigned short As[2][128 * 32];
  __shared__ __align__(16) unsigned short Bs[2][64 * 32];

  const int wave = threadIdx.x >> 6;
  const int lane = threadIdx.x & 63;
  const int lr = lane & 15;
  const int lk = (lane >> 4) * 8;
  const int m0 = blockIdx.x * 128;
  const int n0 = blockIdx.y * 64;
  const int wm = (wave >> 1) * 64;
  const int wn = (wave & 1) * 32;
  const int srow = lane >> 2;
  const int scol = (lane & 3) * 8;

  f32x4 acc[4][2];
  const f32x4 fz = {0.f, 0.f, 0.f, 0.f};
#pragma unroll
  for (int i = 0; i < 4; ++i)
#pragma unroll
    for (int j = 0; j < 2; ++j) acc[i][j] = fz;

#define STAGE_O(bb, kk)                                                       \
  {                                                                           \
    _Pragma("unroll") for (int i = 0; i < 2; ++i) {                           \
      const int c = wave * 2 + i;                                             \
      const int row = c * 16 + srow;                                          \
      gload_lds16(X + (size_t)(m0 + row) * E + (kk) + scol, &As[bb][c * 512]);\
    }                                                                         \
    gload_lds16(Wo + (size_t)(n0 + wave * 16 + srow) * E + (kk) + scol,       \
                &Bs[bb][wave * 512]);                                         \
  }

  STAGE_O(0, 0);
  __syncthreads();
  int buf = 0;
  for (int kk = 0; kk < E; kk += 32) {
    if (kk + 32 < E) STAGE_O(buf ^ 1, kk + 32);
    short8 af[4], bw[2];
#pragma unroll
    for (int i = 0; i < 4; ++i)
      af[i] = *reinterpret_cast<const short8*>(
          &As[buf][(wm + i * 16 + lr) * 32 + lk]);
#pragma unroll
    for (int j = 0; j < 2; ++j)
      bw[j] = *reinterpret_cast<const short8*>(
          &Bs[buf][(wn + j * 16 + lr) * 32 + lk]);
#pragma unroll
    for (int i = 0; i < 4; ++i)
#pragma unroll
      for (int j = 0; j < 2; ++j) acc[i][j] = MFMA16(af[i], bw[j], acc[i][j]);
    __syncthreads();
    buf ^= 1;
  }
#undef STAGE_O

  const int rbase = (lane >> 4) * 4;
#pragma unroll
  for (int i = 0; i < 4; ++i) {
#pragma unroll
    for (int j = 0; j < 2; ++j) {
      const int col = n0 + wn + j * 16 + lr;
#pragma unroll
      for (int r = 0; r < 4; ++r) {
        const int row = m0 + wm + i * 16 + rbase + r;
        out[(size_t)row * E + col] = acc[i][j][r];
      }
    }
  }
}

// ---------------- flash attention (64 q-rows/wave, 2-way KV-split) --------
// grid: (S/128, B*H) x 256 threads. Block = 128 q-rows; wave = (qg, half):
// qg picks 64 q-rows (4 x 16-row groups), half picks keys [half*S/2, ...).
// 8 waves/CU (2/SIMD, R8's proven TLP) with HALF R8's DS-pipe work: 16
// ds_reads feed 64 MFMAs per wave-tile, 16 tiles/wave, 16 barrier rounds.
// K/V staged per half in one shared SM array [kv][half][dbuf] (64 KB),
// global_load_lds + both-sides granule swizzle (K on row bits {0,1,3},
// V on {0,1,2}). Swapped QK^T = mfma(K,Q) with PERMUTED key rows so lane
// (lr,jj) ends holding exactly its PV B-fragment keys (register-only P).
// Softmax in exp2 domain (Q pre-scaled 0.125*log2e), defer-max THR=8,
// row-sum via MFMA ones-trick. Halves merge m/l/acc through the staging
// LDS (overlaid, stride-73 floats) at the end. Vt is [B][H][D][S].
__global__ __launch_bounds__(256) void attn_kernel(
    const unsigned short* __restrict__ Qh, const unsigned short* __restrict__ Kh,
    const unsigned short* __restrict__ Vt, unsigned short* __restrict__ Xb) {
  // SM[kv][half][dbuf][64*64] = 64 KB; reused as float merge buffer at end
  __shared__ __align__(16) unsigned short SM[2][2][2][64 * 64];

  const int wave = threadIdx.x >> 6;
  const int lane = threadIdx.x & 63;
  const int lr = lane & 15;       // q index within 16
  const int jj = lane >> 4;       // fragment k-group (0..3)
  const int lk = jj * 8;
  const int qg = wave & 1;        // q-row group-of-64 within block
  const int half = wave >> 1;     // key half
  constexpr int S2 = S / 2;

  // XCD-aware swizzle (512 blocks, 512%8==0 -> bijective): 64 consecutive
  // remapped blocks = 4 heads per XCD -> 2MB K/V resident in its L2.
  const int lin = blockIdx.x + (blockIdx.y << 4);  // gridDim.x == 16
  const int nlin = (lin & 7) * 64 + (lin >> 3);
  const int qt = nlin & 15;
  const int bh = nlin >> 4;
  const int q0 = qt * 128 + qg * 64;  // wave rows: q0 + g*16 + lr

  short8 qf[4][2];
#pragma unroll
  for (int g = 0; g < 4; ++g) {
    const unsigned short* Qp = Qh + ((size_t)bh * S + q0 + g * 16) * D;
    qf[g][0] = *reinterpret_cast<const short8*>(Qp + (size_t)lr * D + lk);
    qf[g][1] = *reinterpret_cast<const short8*>(Qp + (size_t)lr * D + 32 + lk);
  }

  const unsigned short* Kbase = Kh + (size_t)bh * S * D;
  const unsigned short* Vbase = Vt + (size_t)bh * D * S;

  const f32x4 fz = {0.f, 0.f, 0.f, 0.f};
  const short8 ones = {(short)0x3F80, (short)0x3F80, (short)0x3F80,
                       (short)0x3F80, (short)0x3F80, (short)0x3F80,
                       (short)0x3F80, (short)0x3F80};  // bf16 1.0 x8
  float mrun[4];
  f32x4 acc[4][4], lacc[4];
#pragma unroll
  for (int g = 0; g < 4; ++g) {
    mrun[g] = -3.0e38f;
    lacc[g] = fz;
#pragma unroll
    for (int dt = 0; dt < 4; ++dt) acc[g][dt] = fz;
  }

  // staging: per half, K tile = 8 chunks of 1KB, V tile = 8 chunks; the
  // half's two waves (qg=0,1) each stage 4 K + 4 V chunks. Loop-carried ptrs.
  const int srow = lane >> 3;           // row within chunk (0..7)
  const int sgV = (lane & 7) ^ srow;    // V: swzV(rt) = rt&7 = srow

  const unsigned short* kptr[4];
  const unsigned short* vptr[4];
#pragma unroll
  for (int i = 0; i < 4; ++i) {
    const int c = qg * 4 + i;
    const int sgK = (lane & 7) ^ ((srow & 3) | ((c & 1) << 2));
    kptr[i] = Kbase + (size_t)(half * S2 + c * 8 + srow) * D + sgK * 8;
    vptr[i] = Vbase + (size_t)(c * 8 + srow) * S + half * S2 + sgV * 8;
  }

#define STAGE_KV(bb)                                                          \
  {                                                                           \
    _Pragma("unroll") for (int i = 0; i < 4; ++i) {                           \
      const int c = qg * 4 + i;                                               \
      gload_lds16(kptr[i], &SM[0][half][bb][c * 512]);                        \
      gload_lds16(vptr[i], &SM[1][half][bb][c * 512]);                        \
      kptr[i] += 64 * D;                                                      \
      vptr[i] += 64;                                                          \
    }                                                                         \
  }

  STAGE_KV(0);
  __syncthreads();  // prologue drain: tile 0 ready
  int buf = 0;

  const int rb = ((lr >> 2) << 3) + (lr & 3);  // permuted A-row base
  const int kswz = (lr & 3) | (((lr >> 2) & 1) << 2);  // swzK of all K rows
  const int vswz = lr & 7;                             // swzV of all V rows

  constexpr int NT2 = S2 / 64;  // 16 tiles per wave
  for (int t = 0; t < NT2; ++t) {
    if (t + 1 < NT2) STAGE_KV(buf ^ 1);  // prefetch next tile

    // QK^T for ALL 4 groups first (32 MFMA in flight under softmax below)
    f32x4 sf[4][4];
    __builtin_amdgcn_s_setprio(1);
#pragma unroll
    for (int nt = 0; nt < 4; ++nt) {
      const int r = rb + ((nt & 1) << 2) + ((nt >> 1) << 5);
      short8 kf0 = *reinterpret_cast<const short8*>(
          &SM[0][half][buf][r * 64 + ((jj ^ kswz) * 8)]);
      short8 kf1 = *reinterpret_cast<const short8*>(
          &SM[0][half][buf][r * 64 + (((jj + 4) ^ kswz) * 8)]);
#pragma unroll
      for (int g = 0; g < 4; ++g) {
        f32x4 z = fz;
        z = MFMA16(kf0, qf[g][0], z);  // swapped: col=q, row=permuted key
        z = MFMA16(kf1, qf[g][1], z);
        sf[g][nt] = z;  // key = 8jj + 4*(nt&1) + 32*(nt>>1) + r_, q = lr
      }
    }
    __builtin_amdgcn_s_setprio(0);

    // V fragments (shared by all 4 groups; latency hides under softmax)
    short8 vf0[4], vf1[4];
#pragma unroll
    for (int dt = 0; dt < 4; ++dt) {
      const int r = dt * 16 + lr;
      vf0[dt] = *reinterpret_cast<const short8*>(
          &SM[1][half][buf][r * 64 + ((jj ^ vswz) * 8)]);
      vf1[dt] = *reinterpret_cast<const short8*>(
          &SM[1][half][buf][r * 64 + (((jj + 4) ^ vswz) * 8)]);
    }

    // per-group softmax -> pack -> PV
#pragma unroll
    for (int g = 0; g < 4; ++g) {
      float tm[4];
#pragma unroll
      for (int nt = 0; nt < 4; ++nt)
        tm[nt] = fmaxf(fmaxf(sf[g][nt][0], sf[g][nt][1]),
                       fmaxf(sf[g][nt][2], sf[g][nt][3]));
      float mx = fmaxf(fmaxf(tm[0], tm[1]), fmaxf(tm[2], tm[3]));
      mx = fmaxf(mx, __shfl_xor(mx, 16));
      mx = fmaxf(mx, __shfl_xor(mx, 32));
      if (__any(mx > mrun[g] + 8.f)) {
        const float nm = fmaxf(mrun[g], mx);
        const float fac = __builtin_amdgcn_exp2f(mrun[g] - nm);
        mrun[g] = nm;
        lacc[g] *= fac;
#pragma unroll
        for (int dt = 0; dt < 4; ++dt)
#pragma unroll
          for (int r = 0; r < 4; ++r) acc[g][dt][r] *= fac;
      }
#pragma unroll
      for (int nt = 0; nt < 4; ++nt)
#pragma unroll
        for (int r = 0; r < 4; ++r)
          sf[g][nt][r] = __builtin_amdgcn_exp2f(sf[g][nt][r] - mrun[g]);
      i32x4 w0, w1;
      w0.x = cvt_pk_bf16(sf[g][0][0], sf[g][0][1]);
      w0.y = cvt_pk_bf16(sf[g][0][2], sf[g][0][3]);
      w0.z = cvt_pk_bf16(sf[g][1][0], sf[g][1][1]);
      w0.w = cvt_pk_bf16(sf[g][1][2], sf[g][1][3]);
      w1.x = cvt_pk_bf16(sf[g][2][0], sf[g][2][1]);
      w1.y = cvt_pk_bf16(sf[g][2][2], sf[g][2][3]);
      w1.z = cvt_pk_bf16(sf[g][3][0], sf[g][3][1]);
      w1.w = cvt_pk_bf16(sf[g][3][2], sf[g][3][3]);
      const short8 pa0 = __builtin_bit_cast(short8, w0);
      const short8 pa1 = __builtin_bit_cast(short8, w1);

      __builtin_amdgcn_s_setprio(1);
#pragma unroll
      for (int dt = 0; dt < 4; ++dt) {
        acc[g][dt] = MFMA16(vf0[dt], pa0, acc[g][dt]);  // col=q, row=d
        acc[g][dt] = MFMA16(vf1[dt], pa1, acc[g][dt]);
      }
      lacc[g] = MFMA16(ones, pa0, lacc[g]);  // all rows = Sum_k P[k][q]
      lacc[g] = MFMA16(ones, pa1, lacc[g]);
      __builtin_amdgcn_s_setprio(0);
    }

    __syncthreads();  // next tile staged (vmcnt drained) + reads done
    buf ^= 1;
  }
#undef STAGE_KV

  // ---- merge the two key-halves of each q-group through overlaid LDS ----
  // Layout: Mg[(qg*64 + lane)*73 + idx]; idx 0..63 = acc, 64..67 = m,
  // 68..71 = l. Stride 73 (odd) -> conflict-free. 37376 B <= 64 KB.
  float* Mg = (float*)&SM[0][0][0][0];
  if (half == 1) {
    float* p = Mg + (size_t)(qg * 64 + lane) * 73;
#pragma unroll
    for (int g = 0; g < 4; ++g) {
#pragma unroll
      for (int dt = 0; dt < 4; ++dt)
#pragma unroll
        for (int r = 0; r < 4; ++r) p[g * 16 + dt * 4 + r] = acc[g][dt][r];
      p[64 + g] = mrun[g];
      p[68 + g] = lacc[g][0];
    }
  }
  __syncthreads();
  if (half == 0) {
    const float* p = Mg + (size_t)(qg * 64 + lane) * 73;
    const int b = bh >> 4, h = bh & (H - 1);
#pragma unroll
    for (int g = 0; g < 4; ++g) {
      const float mB = p[64 + g];
      const float lB = p[68 + g];
      const float nm = fmaxf(mrun[g], mB);
      const float fa = __builtin_amdgcn_exp2f(mrun[g] - nm);
      const float fb = __builtin_amdgcn_exp2f(mB - nm);
      const float inv = 1.0f / (lacc[g][0] * fa + lB * fb);
      const int row = q0 + g * 16 + lr;
#pragma unroll
      for (int dt = 0; dt < 4; ++dt) {
        us4 o;
#pragma unroll
        for (int r = 0; r < 4; ++r)
          o[r] = f2bf((acc[g][dt][r] * fa + p[g * 16 + dt * 4 + r] * fb) * inv);
        *reinterpret_cast<us4*>(
            &Xb[((size_t)b * S + row) * E + h * D + dt * 16 + 4 * jj]) = o;
      }
    }
  }
}

extern "C" void kernel_launch(void* const* d_in, const int* in_sizes, int n_in,
                              void* d_out, int out_size, void* d_ws, size_t ws_size,
                              hipStream_t stream) {
  const float* q_f = (const float*)d_in[0];
  const float* k_f = (const float*)d_in[1];
  const float* v_f = (const float*)d_in[2];
  const float* wq_f = (const float*)d_in[3];
  const float* wk_f = (const float*)d_in[4];
  const float* wv_f = (const float*)d_in[5];
  const float* wo_f = (const float*)d_in[6];

  // workspace layout (bf16 halves): 7*NE + 4*NW elements = 64 MB
  unsigned short* xq = (unsigned short*)d_ws;
  unsigned short* xk = xq + NE;
  unsigned short* xv = xk + NE;
  unsigned short* wq = xv + NE;
  unsigned short* wk = wq + NW;
  unsigned short* wv = wk + NW;
  unsigned short* wo = wv + NW;
  unsigned short* Qh = wo + NW;
  unsigned short* Kh = Qh + NE;
  unsigned short* Vt = Kh + NE;
  unsigned short* Xb = Vt + NE;

  // 1) convert inputs + weights to bf16 (single launch)
  cvt_all_kernel<<<dim3(512, 7), 256, 0, stream>>>(
      q_f, k_f, v_f, wq_f, wk_f, wv_f, wo_f, xq, xk, xv, wq, wk, wv, wo,
      (int)(NE / 4), (int)(NW / 4));

  // 2) fused Q/K/V projections (768 blocks = 3 blocks/CU)
  gemm_proj_kernel<<<dim3(M / 128, E / 128, 3), 256, 0, stream>>>(
      xq, xk, xv, wq, wk, wv, Qh, Kh, Vt);

  // 3) flash attention (64 q-rows/wave, 2-way KV-split, MFMA row-sum)
  attn_kernel<<<dim3(S / 128, B * H), 256, 0, stream>>>(Qh, Kh, Vt, Xb);

  // 4) output projection (512 blocks = 2 blocks/CU, fp32 out)
  gemm_out_kernel<<<dim3(M / 128, E / 64), 256, 0, stream>>>(Xb, wo,
                                                             (float*)d_out);
}

// Round 15
// 143.505 us; speedup vs baseline: 1.1235x; 1.1235x over previous
//
#include <hip/hip_runtime.h>
#include <hip/hip_bf16.h>

// MHA: out = softmax((x@Wq^T)(x@Wk^T)^T / sqrt(D)) (x@Wv^T) @ Wo^T
// B=2, S=2048, E=1024, H=16, D=64.
// This is the R10 kernel, byte-exact (last proven: 143.9 us, absmax 1.22e-3).
// R12-R14 post-mortems: (a) plain-VMEM MFMA-operand loads mixed with
// global_load_lds staging in the same loop produce races on this toolchain;
// (b) 2-tiles-per-barrier pair staging also races. The safe configuration
// is 1 tile per barrier round, all operands through LDS.

typedef __attribute__((ext_vector_type(8))) short short8;
typedef __attribute__((ext_vector_type(4))) float f32x4;
typedef __attribute__((ext_vector_type(4))) unsigned short us4;
typedef __attribute__((ext_vector_type(4))) int i32x4;

#define MFMA16(a, b, c) __builtin_amdgcn_mfma_f32_16x16x32_bf16(a, b, c, 0, 0, 0)

static constexpr int B = 2;
static constexpr int S = 2048;
static constexpr int E = 1024;
static constexpr int H = 16;
static constexpr int D = 64;
static constexpr int M = B * S;               // 4096 rows in projection GEMMs
static constexpr size_t NE = (size_t)M * E;   // activation elements
static constexpr size_t NW = (size_t)E * E;   // weight elements

// round-to-nearest-even fp32 -> bf16 (bit pattern as ushort)
static __device__ __forceinline__ unsigned short f2bf(float x) {
  unsigned int u = __float_as_uint(x);
  unsigned int r = (u + 0x7FFFu + ((u >> 16) & 1u)) >> 16;
  return (unsigned short)r;
}

// packed fp32x2 -> bf16x2 (RNE), single HW instruction; lo in low 16 bits
static __device__ __forceinline__ int cvt_pk_bf16(float lo, float hi) {
  int r;
  asm("v_cvt_pk_bf16_f32 %0, %1, %2" : "=v"(r) : "v"(lo), "v"(hi));
  return r;
}

// async global -> LDS, 16B per lane. LDS dest = wave-uniform base + lane*16.
static __device__ __forceinline__ void gload_lds16(const unsigned short* g,
                                                   unsigned short* l) {
  __builtin_amdgcn_global_load_lds(
      (const __attribute__((address_space(1))) unsigned int*)g,
      (__attribute__((address_space(3))) unsigned int*)l, 16, 0, 0);
}

// ---------------- fp32 -> bf16 conversion (single launch, z-indexed) ------
__global__ void cvt_all_kernel(const float* __restrict__ s0,
                               const float* __restrict__ s1,
                               const float* __restrict__ s2,
                               const float* __restrict__ s3,
                               const float* __restrict__ s4,
                               const float* __restrict__ s5,
                               const float* __restrict__ s6,
                               unsigned short* __restrict__ d0,
                               unsigned short* __restrict__ d1,
                               unsigned short* __restrict__ d2,
                               unsigned short* __restrict__ d3,
                               unsigned short* __restrict__ d4,
                               unsigned short* __restrict__ d5,
                               unsigned short* __restrict__ d6, int nAct4,
                               int nW4) {
  const int z = blockIdx.y;
  const float* srcs[7] = {s0, s1, s2, s3, s4, s5, s6};
  unsigned short* dsts[7] = {d0, d1, d2, d3, d4, d5, d6};
  const float* src = srcs[z];
  unsigned short* dst = dsts[z];
  const int n4 = (z < 3) ? nAct4 : nW4;
  for (int i = blockIdx.x * blockDim.x + threadIdx.x; i < n4;
       i += gridDim.x * blockDim.x) {
    float4 v = reinterpret_cast<const float4*>(src)[i];
    ushort4 o;
    o.x = f2bf(v.x); o.y = f2bf(v.y); o.z = f2bf(v.z); o.w = f2bf(v.w);
    reinterpret_cast<ushort4*>(dst)[i] = o;
  }
}

// ---------------- fused QKV projection GEMM (double-buffered) -------------
// grid (M/128, E/128, 3). 128x128 tile, BK=32, 4 waves 2x2, global_load_lds
// staging, 2-phase: STAGE(next) -> compute(cur) -> one barrier per K-step.
// z==0: Q -> Qh[B][H][S][D] * 0.125*log2(e)   z==1: K -> Kh[B][H][S][D]
// z==2: V -> Vt[B][H][D][S]
__global__ __launch_bounds__(256) void gemm_proj_kernel(
    const unsigned short* __restrict__ xq, const unsigned short* __restrict__ xk,
    const unsigned short* __restrict__ xv, const unsigned short* __restrict__ wq,
    const unsigned short* __restrict__ wk, const unsigned short* __restrict__ wv,
    unsigned short* __restrict__ Qh, unsigned short* __restrict__ Kh,
    unsigned short* __restrict__ Vt) {
  __shared__ __align__(16) unsigned short As[2][128 * 32];
  __shared__ __align__(16) unsigned short Bs[2][128 * 32];

  const int which = blockIdx.z;
  const unsigned short* A = (which == 0) ? xq : ((which == 1) ? xk : xv);
  const unsigned short* W = (which == 0) ? wq : ((which == 1) ? wk : wv);

  const int wave = threadIdx.x >> 6;
  const int lane = threadIdx.x & 63;
  const int lr = lane & 15;
  const int lk = (lane >> 4) * 8;
  const int m0 = blockIdx.x * 128;
  const int n0 = blockIdx.y * 128;
  const int wm = (wave >> 1) * 64;
  const int wn = (wave & 1) * 64;
  const int srow = lane >> 2;        // row within 16-row staging chunk
  const int scol = (lane & 3) * 8;   // element col within BK=32

  f32x4 acc[4][4];
  const f32x4 fz = {0.f, 0.f, 0.f, 0.f};
#pragma unroll
  for (int i = 0; i < 4; ++i)
#pragma unroll
    for (int j = 0; j < 4; ++j) acc[i][j] = fz;

#define STAGE_G(bb, kk)                                                       \
  {                                                                           \
    _Pragma("unroll") for (int i = 0; i < 2; ++i) {                           \
      const int c = wave * 2 + i;                                             \
      const int row = c * 16 + srow;                                          \
      gload_lds16(A + (size_t)(m0 + row) * E + (kk) + scol, &As[bb][c * 512]);\
      gload_lds16(W + (size_t)(n0 + row) * E + (kk) + scol, &Bs[bb][c * 512]);\
    }                                                                         \
  }

  STAGE_G(0, 0);
  __syncthreads();
  int buf = 0;
  for (int kk = 0; kk < E; kk += 32) {
    if (kk + 32 < E) STAGE_G(buf ^ 1, kk + 32);  // prefetch next K-tile
    short8 af[4], bw[4];
#pragma unroll
    for (int i = 0; i < 4; ++i)
      af[i] = *reinterpret_cast<const short8*>(
          &As[buf][(wm + i * 16 + lr) * 32 + lk]);
#pragma unroll
    for (int j = 0; j < 4; ++j)
      bw[j] = *reinterpret_cast<const short8*>(
          &Bs[buf][(wn + j * 16 + lr) * 32 + lk]);
#pragma unroll
    for (int i = 0; i < 4; ++i)
#pragma unroll
      for (int j = 0; j < 4; ++j) acc[i][j] = MFMA16(af[i], bw[j], acc[i][j]);
    __syncthreads();  // drains vmcnt(0): next tile staged; reads done
    buf ^= 1;
  }
#undef STAGE_G

  const int rbase = (lane >> 4) * 4;
#pragma unroll
  for (int i = 0; i < 4; ++i) {
#pragma unroll
    for (int j = 0; j < 4; ++j) {
      const int col = n0 + wn + j * 16 + lr;
      const int h = col >> 6, d = col & 63;
#pragma unroll
      for (int r = 0; r < 4; ++r) {
        const int row = m0 + wm + i * 16 + rbase + r;
        const int b = row >> 11, s = row & (S - 1);
        const float v = acc[i][j][r];
        if (which == 0) {
          // 0.125 * log2(e): QK scores land in log2 domain for native v_exp
          Qh[(((size_t)b * H + h) * S + s) * D + d] = f2bf(v * 0.18033688f);
        } else if (which == 1) {
          Kh[(((size_t)b * H + h) * S + s) * D + d] = f2bf(v);
        } else {
          Vt[(((size_t)b * H + h) * D + d) * S + s] = f2bf(v);
        }
      }
    }
  }
}

// ---------------- output GEMM: out = X @ Wo^T (128x64 tile, dbuf) ---------
// grid (M/128, E/64) = 512 blocks -> 2 blocks/CU for overlap.
__global__ __launch_bounds__(256) void gemm_out_kernel(
    const unsigned short* __restrict__ X, const unsigned short* __restrict__ Wo,
    float* __restrict__ out) {
  __shared__ __align__(16) unsigned short As[2][128 * 32];
  __shared__ __align__(16) unsigned short Bs[2][64 * 32];

  const int wave = threadIdx.x >> 6;
  const int lane = threadIdx.x & 63;
  const int lr = lane & 15;
  const int lk = (lane >> 4) * 8;
  const int m0 = blockIdx.x * 128;
  const int n0 = blockIdx.y * 64;
  const int wm = (wave >> 1) * 64;
  const int wn = (wave & 1) * 32;
  const int srow = lane >> 2;
  const int scol = (lane & 3) * 8;

  f32x4 acc[4][2];
  const f32x4 fz = {0.f, 0.f, 0.f, 0.f};
#pragma unroll
  for (int i = 0; i < 4; ++i)
#pragma unroll
    for (int j = 0; j < 2; ++j) acc[i][j] = fz;

#define STAGE_O(bb, kk)                                                       \
  {                                                                           \
    _Pragma("unroll") for (int i = 0; i < 2; ++i) {                           \
      const int c = wave * 2 + i;                                             \
      const int row = c * 16 + srow;                                          \
      gload_lds16(X + (size_t)(m0 + row) * E + (kk) + scol, &As[bb][c * 512]);\
    }                                                                         \
    gload_lds16(Wo + (size_t)(n0 + wave * 16 + srow) * E + (kk) + scol,       \
                &Bs[bb][wave * 512]);                                         \
  }

  STAGE_O(0, 0);
  __syncthreads();
  int buf = 0;
  for (int kk = 0; kk < E; kk += 32) {
    if (kk + 32 < E) STAGE_O(buf ^ 1, kk + 32);
    short8 af[4], bw[2];
#pragma unroll
    for (int i = 0; i < 4; ++i)
      af[i] = *reinterpret_cast<const short8*>(
          &As[buf][(wm + i * 16 + lr) * 32 + lk]);
#pragma unroll
    for (int j = 0; j < 2; ++j)
      bw[j] = *reinterpret_cast<const short8*>(
          &Bs[buf][(wn + j * 16 + lr) * 32 + lk]);
#pragma unroll
    for (int i = 0; i < 4; ++i)
#pragma unroll
      for (int j = 0; j < 2; ++j) acc[i][j] = MFMA16(af[i], bw[j], acc[i][j]);
    __syncthreads();
    buf ^= 1;
  }
#undef STAGE_O

  const int rbase = (lane >> 4) * 4;
#pragma unroll
  for (int i = 0; i < 4; ++i) {
#pragma unroll
    for (int j = 0; j < 2; ++j) {
      const int col = n0 + wn + j * 16 + lr;
#pragma unroll
      for (int r = 0; r < 4; ++r) {
        const int row = m0 + wm + i * 16 + rbase + r;
        out[(size_t)row * E + col] = acc[i][j][r];
      }
    }
  }
}

// ---------------- flash attention (32 q-rows/wave, MFMA row-sum) ----------
// grid: (S/128, B*H) x 256 threads (4 waves x 32 q-rows; the proven
// TLP/ds-amortization optimum: 2 waves/SIMD, 16 ds_reads -> 32 MFMAs per
// wave-tile). K/V tiles [64x64] staged once per block (double-buffered,
// global_load_lds, both-sides granule swizzle; K swizzle on row bits
// {0,1,3}, V on {0,1,2}).
// Swapped QK^T = mfma(K,Q) with PERMUTED key rows so lane (lr,jj) ends
// holding exactly its PV B-fragment keys -> P never leaves the lane.
// Softmax in exp2 domain (Q pre-scaled by 0.125*log2e), defer-max THR=8.
// Row-sum via MFMA ones-trick: lacc = mfma(ones, pa, lacc) -> every lane of
// a q-row gets Sum_k P[k][q]. PV = mfma(V^T, P^T). Vt is [B][H][D][S].
__global__ __launch_bounds__(256) void attn_kernel(
    const unsigned short* __restrict__ Qh, const unsigned short* __restrict__ Kh,
    const unsigned short* __restrict__ Vt, unsigned short* __restrict__ Xb) {
  __shared__ __align__(16) unsigned short Ks[2][64 * 64];
  __shared__ __align__(16) unsigned short Vs[2][64 * 64];

  const int wave = threadIdx.x >> 6;
  const int lane = threadIdx.x & 63;
  const int lr = lane & 15;       // q index within 16
  const int jj = lane >> 4;       // fragment k-group (0..3)
  const int lk = jj * 8;

  // XCD-aware swizzle (512 blocks, 512%8==0 -> bijective): 64 consecutive
  // remapped blocks = 4 heads per XCD -> 2MB K/V resident in its L2.
  const int lin = blockIdx.x + (blockIdx.y << 4);  // gridDim.x == 16
  const int nlin = (lin & 7) * 64 + (lin >> 3);
  const int qt = nlin & 15;
  const int bh = nlin >> 4;
  const int q0 = qt * 128 + wave * 32;  // wave rows: q0+lr (A), q0+16+lr (B)

  const unsigned short* Qp0 = Qh + ((size_t)bh * S + q0) * D;
  const unsigned short* Qp1 = Qp0 + (size_t)16 * D;
  short8 qa0 = *reinterpret_cast<const short8*>(Qp0 + (size_t)lr * D + lk);
  short8 qa1 = *reinterpret_cast<const short8*>(Qp0 + (size_t)lr * D + 32 + lk);
  short8 qb0 = *reinterpret_cast<const short8*>(Qp1 + (size_t)lr * D + lk);
  short8 qb1 = *reinterpret_cast<const short8*>(Qp1 + (size_t)lr * D + 32 + lk);

  const unsigned short* Kbase = Kh + (size_t)bh * S * D;
  const unsigned short* Vbase = Vt + (size_t)bh * D * S;

  const f32x4 fz = {0.f, 0.f, 0.f, 0.f};
  const short8 ones = {(short)0x3F80, (short)0x3F80, (short)0x3F80,
                       (short)0x3F80, (short)0x3F80, (short)0x3F80,
                       (short)0x3F80, (short)0x3F80};  // bf16 1.0 x8
  float mrunA = -3.0e38f, mrunB = -3.0e38f;
  f32x4 accA[4], accB[4], laccA = fz, laccB = fz;
#pragma unroll
  for (int dt = 0; dt < 4; ++dt) { accA[dt] = fz; accB[dt] = fz; }

  // staging geometry: 8 chunks of 1KB per tile (8 rows x 128B each).
  // LDS[row][slot] holds global granule slot^swz(row); read granule g of
  // row r at slot g^swz(r). Pointers are loop-carried (+= stride per tile).
  const int srow = lane >> 3;           // row within chunk (0..7)
  const int sgV = (lane & 7) ^ srow;    // V: swzV(rt) = rt&7 = srow

  const unsigned short* kptr[2];
  const unsigned short* vptr[2];
#pragma unroll
  for (int i = 0; i < 2; ++i) {
    const int c = wave * 2 + i;
    const int sgK = (lane & 7) ^ ((srow & 3) | ((c & 1) << 2));
    kptr[i] = Kbase + (size_t)(c * 8 + srow) * D + sgK * 8;
    vptr[i] = Vbase + (size_t)(c * 8 + srow) * S + sgV * 8;
  }

#define STAGE_KV(bb)                                                          \
  {                                                                           \
    _Pragma("unroll") for (int i = 0; i < 2; ++i) {                           \
      const int c = wave * 2 + i;                                             \
      gload_lds16(kptr[i], &Ks[bb][c * 512]);                                 \
      gload_lds16(vptr[i], &Vs[bb][c * 512]);                                 \
      kptr[i] += 64 * D;                                                      \
      vptr[i] += 64;                                                          \
    }                                                                         \
  }

  STAGE_KV(0);
  __syncthreads();  // prologue drain: tile 0 ready
  int buf = 0;

  const int rb = ((lr >> 2) << 3) + (lr & 3);  // permuted A-row base
  const int kswz = (lr & 3) | (((lr >> 2) & 1) << 2);  // swzK of all K rows
  const int vswz = lr & 7;                             // swzV of all V rows

  constexpr int NT = S / 64;
  for (int t = 0; t < NT; ++t) {
    if (t + 1 < NT) STAGE_KV(buf ^ 1);  // prefetch next tile

    // QK^T from LDS K (swizzled read, permuted key rows); kf shared by A,B
    f32x4 sfA[4], sfB[4];
    __builtin_amdgcn_s_setprio(1);
#pragma unroll
    for (int nt = 0; nt < 4; ++nt) {
      const int r = rb + ((nt & 1) << 2) + ((nt >> 1) << 5);
      short8 kf0 = *reinterpret_cast<const short8*>(
          &Ks[buf][r * 64 + ((jj ^ kswz) * 8)]);
      short8 kf1 = *reinterpret_cast<const short8*>(
          &Ks[buf][r * 64 + (((jj + 4) ^ kswz) * 8)]);
      f32x4 za = fz, zb = fz;
      za = MFMA16(kf0, qa0, za);   // swapped: col=q, row=permuted key
      za = MFMA16(kf1, qa1, za);
      zb = MFMA16(kf0, qb0, zb);
      zb = MFMA16(kf1, qb1, zb);
      sfA[nt] = za;  // key = 8jj + 4*(nt&1) + 32*(nt>>1) + r_, q = lr
      sfB[nt] = zb;  // same keys, q = lr + 16
    }
    __builtin_amdgcn_s_setprio(0);

    // V fragments from LDS (issued early; latency hides under softmax)
    short8 vf0[4], vf1[4];
#pragma unroll
    for (int dt = 0; dt < 4; ++dt) {
      const int r = dt * 16 + lr;
      vf0[dt] = *reinterpret_cast<const short8*>(
          &Vs[buf][r * 64 + ((jj ^ vswz) * 8)]);
      vf1[dt] = *reinterpret_cast<const short8*>(
          &Vs[buf][r * 64 + (((jj + 4) ^ vswz) * 8)]);
    }

    // ---- softmax, q-group A (tree max: depth 4, width 8) ----
    float tA[4];
#pragma unroll
    for (int nt = 0; nt < 4; ++nt)
      tA[nt] = fmaxf(fmaxf(sfA[nt][0], sfA[nt][1]),
                     fmaxf(sfA[nt][2], sfA[nt][3]));
    float mxA = fmaxf(fmaxf(tA[0], tA[1]), fmaxf(tA[2], tA[3]));
    mxA = fmaxf(mxA, __shfl_xor(mxA, 16));
    mxA = fmaxf(mxA, __shfl_xor(mxA, 32));
    if (__any(mxA > mrunA + 8.f)) {
      const float nm = fmaxf(mrunA, mxA);
      const float fac = __builtin_amdgcn_exp2f(mrunA - nm);
      mrunA = nm;
      laccA *= fac;
#pragma unroll
      for (int dt = 0; dt < 4; ++dt)
#pragma unroll
        for (int r = 0; r < 4; ++r) accA[dt][r] *= fac;
    }
#pragma unroll
    for (int nt = 0; nt < 4; ++nt)
#pragma unroll
      for (int r = 0; r < 4; ++r)
        sfA[nt][r] = __builtin_amdgcn_exp2f(sfA[nt][r] - mrunA);
    i32x4 wa0, wa1;
    wa0.x = cvt_pk_bf16(sfA[0][0], sfA[0][1]);
    wa0.y = cvt_pk_bf16(sfA[0][2], sfA[0][3]);
    wa0.z = cvt_pk_bf16(sfA[1][0], sfA[1][1]);
    wa0.w = cvt_pk_bf16(sfA[1][2], sfA[1][3]);
    wa1.x = cvt_pk_bf16(sfA[2][0], sfA[2][1]);
    wa1.y = cvt_pk_bf16(sfA[2][2], sfA[2][3]);
    wa1.z = cvt_pk_bf16(sfA[3][0], sfA[3][1]);
    wa1.w = cvt_pk_bf16(sfA[3][2], sfA[3][3]);
    const short8 paA0 = __builtin_bit_cast(short8, wa0);
    const short8 paA1 = __builtin_bit_cast(short8, wa1);

    // ---- softmax, q-group B ----
    float tB[4];
#pragma unroll
    for (int nt = 0; nt < 4; ++nt)
      tB[nt] = fmaxf(fmaxf(sfB[nt][0], sfB[nt][1]),
                     fmaxf(sfB[nt][2], sfB[nt][3]));
    float mxB = fmaxf(fmaxf(tB[0], tB[1]), fmaxf(tB[2], tB[3]));
    mxB = fmaxf(mxB, __shfl_xor(mxB, 16));
    mxB = fmaxf(mxB, __shfl_xor(mxB, 32));
    if (__any(mxB > mrunB + 8.f)) {
      const float nm = fmaxf(mrunB, mxB);
      const float fac = __builtin_amdgcn_exp2f(mrunB - nm);
      mrunB = nm;
      laccB *= fac;
#pragma unroll
      for (int dt = 0; dt < 4; ++dt)
#pragma unroll
        for (int r = 0; r < 4; ++r) accB[dt][r] *= fac;
    }
#pragma unroll
    for (int nt = 0; nt < 4; ++nt)
#pragma unroll
      for (int r = 0; r < 4; ++r)
        sfB[nt][r] = __builtin_amdgcn_exp2f(sfB[nt][r] - mrunB);
    i32x4 wb0, wb1;
    wb0.x = cvt_pk_bf16(sfB[0][0], sfB[0][1]);
    wb0.y = cvt_pk_bf16(sfB[0][2], sfB[0][3]);
    wb0.z = cvt_pk_bf16(sfB[1][0], sfB[1][1]);
    wb0.w = cvt_pk_bf16(sfB[1][2], sfB[1][3]);
    wb1.x = cvt_pk_bf16(sfB[2][0], sfB[2][1]);
    wb1.y = cvt_pk_bf16(sfB[2][2], sfB[2][3]);
    wb1.z = cvt_pk_bf16(sfB[3][0], sfB[3][1]);
    wb1.w = cvt_pk_bf16(sfB[3][2], sfB[3][3]);
    const short8 paB0 = __builtin_bit_cast(short8, wb0);
    const short8 paB1 = __builtin_bit_cast(short8, wb1);

    // ---- PV + row-sum (vf shared by both q-groups; lacc via ones-trick) --
    __builtin_amdgcn_s_setprio(1);
#pragma unroll
    for (int dt = 0; dt < 4; ++dt) {
      accA[dt] = MFMA16(vf0[dt], paA0, accA[dt]);  // swapped: col=q, row=d
      accA[dt] = MFMA16(vf1[dt], paA1, accA[dt]);
      accB[dt] = MFMA16(vf0[dt], paB0, accB[dt]);
      accB[dt] = MFMA16(vf1[dt], paB1, accB[dt]);
    }
    laccA = MFMA16(ones, paA0, laccA);  // rows all = Sum_k P[k][q]
    laccA = MFMA16(ones, paA1, laccA);
    laccB = MFMA16(ones, paB0, laccB);
    laccB = MFMA16(ones, paB1, laccB);
    __builtin_amdgcn_s_setprio(0);

    __syncthreads();  // next tile staged (vmcnt drained) + reads done
    buf ^= 1;
  }
#undef STAGE_KV

  // normalize and store (lacc already holds the full row sum in every lane)
  const int b = bh >> 4, h = bh & (H - 1);
  {
    const float inv = 1.0f / laccA[0];
    const int row = q0 + lr;
#pragma unroll
    for (int dt = 0; dt < 4; ++dt) {
      us4 o;
#pragma unroll
      for (int r = 0; r < 4; ++r) o[r] = f2bf(accA[dt][r] * inv);
      *reinterpret_cast<us4*>(
          &Xb[((size_t)b * S + row) * E + h * D + dt * 16 + 4 * jj]) = o;
    }
  }
  {
    const float inv = 1.0f / laccB[0];
    const int row = q0 + 16 + lr;
#pragma unroll
    for (int dt = 0; dt < 4; ++dt) {
      us4 o;
#pragma unroll
      for (int r = 0; r < 4; ++r) o[r] = f2bf(accB[dt][r] * inv);
      *reinterpret_cast<us4*>(
          &Xb[((size_t)b * S + row) * E + h * D + dt * 16 + 4 * jj]) = o;
    }
  }
}

extern "C" void kernel_launch(void* const* d_in, const int* in_sizes, int n_in,
                              void* d_out, int out_size, void* d_ws, size_t ws_size,
                              hipStream_t stream) {
  const float* q_f = (const float*)d_in[0];
  const float* k_f = (const float*)d_in[1];
  const float* v_f = (const float*)d_in[2];
  const float* wq_f = (const float*)d_in[3];
  const float* wk_f = (const float*)d_in[4];
  const float* wv_f = (const float*)d_in[5];
  const float* wo_f = (const float*)d_in[6];

  // workspace layout (bf16 halves): 7*NE + 4*NW elements = 64 MB
  unsigned short* xq = (unsigned short*)d_ws;
  unsigned short* xk = xq + NE;
  unsigned short* xv = xk + NE;
  unsigned short* wq = xv + NE;
  unsigned short* wk = wq + NW;
  unsigned short* wv = wk + NW;
  unsigned short* wo = wv + NW;
  unsigned short* Qh = wo + NW;
  unsigned short* Kh = Qh + NE;
  unsigned short* Vt = Kh + NE;
  unsigned short* Xb = Vt + NE;

  // 1) convert inputs + weights to bf16 (single launch)
  cvt_all_kernel<<<dim3(512, 7), 256, 0, stream>>>(
      q_f, k_f, v_f, wq_f, wk_f, wv_f, wo_f, xq, xk, xv, wq, wk, wv, wo,
      (int)(NE / 4), (int)(NW / 4));

  // 2) fused Q/K/V projections (768 blocks = 3 blocks/CU)
  gemm_proj_kernel<<<dim3(M / 128, E / 128, 3), 256, 0, stream>>>(
      xq, xk, xv, wq, wk, wv, Qh, Kh, Vt);

  // 3) flash attention (32 q-rows/wave, 4-wave blocks, MFMA row-sum)
  attn_kernel<<<dim3(S / 128, B * H), 256, 0, stream>>>(Qh, Kh, Vt, Xb);

  // 4) output projection (512 blocks = 2 blocks/CU, fp32 out)
  gemm_out_kernel<<<dim3(M / 128, E / 64), 256, 0, stream>>>(Xb, wo,
                                                             (float*)d_out);
}